// Round 1
// baseline (13834.906 us; speedup 1.0000x reference)
//
#include <hip/hip_runtime.h>
#include <stdint.h>

// Problem constants
// T=512, B=32, I=1024, H=1024, G=4H=4096
// out: [512][32][2048] fp32 then hf[32][1024], cf, hb, cb  (total 33685504 f32)

using short8 = __attribute__((ext_vector_type(8))) short;   // 8 bf16
using f32x4  = __attribute__((ext_vector_type(4))) float;

typedef unsigned int uint;
typedef unsigned short ushort;

// ---------------- ws layout (bytes) ----------------
#define OFF_XB      0ull            // x as bf16: 16777216 * 2 = 33554432
#define OFF_WIH_F   33554432ull     // 4096*1024*2 = 8388608
#define OFF_WIH_B   41943040ull
#define OFF_WHH_F   50331648ull
#define OFF_WHH_B   58720256ull
#define OFF_BSUM_F  67108864ull     // 4096 * 4
#define OFF_BSUM_B  67125248ull
#define OFF_HBUF    67141632ull     // 2 dir * 2 parity * 32*1024 * 2B = 262144
#define OFF_CBUF    67403776ull     // 2 * 32*1024 * 4B = 262144
#define OFF_FLAGS   67665920ull     // 64 uints (padded)
#define OFF_XG      67670016ull     // fp16 xg: 2 * csteps*32*4096*2

__device__ __forceinline__ ushort f2bf(float f) {
    uint u = __float_as_uint(f);
    u += 0x7fffu + ((u >> 16) & 1u);   // RNE
    return (ushort)(u >> 16);
}
__device__ __forceinline__ float sigmoidf_(float x) { return 1.0f / (1.0f + expf(-x)); }

// ---------------- prep: fp32 -> bf16 converts, bias sums, h0, flags ----------------
__global__ __launch_bounds__(256) void prep_kernel(
    const float* __restrict__ x,
    const float* __restrict__ wih_f, const float* __restrict__ whh_f,
    const float* __restrict__ bih_f, const float* __restrict__ bhh_f,
    const float* __restrict__ wih_b, const float* __restrict__ whh_b,
    const float* __restrict__ bih_b, const float* __restrict__ bhh_b,
    const float* __restrict__ h0f, const float* __restrict__ h0b,
    char* __restrict__ ws)
{
    int r = blockIdx.x * 256 + threadIdx.x;
    const int n_x = 16777216, n_w = 4194304;
    if (r < n_x) { ((ushort*)(ws + OFF_XB))[r] = f2bf(x[r]); return; }
    r -= n_x;
    if (r < n_w) { ((ushort*)(ws + OFF_WIH_F))[r] = f2bf(wih_f[r]); return; }
    r -= n_w;
    if (r < n_w) { ((ushort*)(ws + OFF_WIH_B))[r] = f2bf(wih_b[r]); return; }
    r -= n_w;
    if (r < n_w) { ((ushort*)(ws + OFF_WHH_F))[r] = f2bf(whh_f[r]); return; }
    r -= n_w;
    if (r < n_w) { ((ushort*)(ws + OFF_WHH_B))[r] = f2bf(whh_b[r]); return; }
    r -= n_w;
    if (r < 4096) { ((float*)(ws + OFF_BSUM_F))[r] = bih_f[r] + bhh_f[r]; return; }
    r -= 4096;
    if (r < 4096) { ((float*)(ws + OFF_BSUM_B))[r] = bih_b[r] + bhh_b[r]; return; }
    r -= 4096;
    if (r < 32768) { ((ushort*)(ws + OFF_HBUF))[r] = f2bf(h0f[r]); return; }          // dir0,parity0
    r -= 32768;
    if (r < 32768) { ((ushort*)(ws + OFF_HBUF))[2 * 32768 + r] = f2bf(h0b[r]); return; } // dir1,parity0
    r -= 32768;
    if (r < 64) { ((uint*)(ws + OFF_FLAGS))[r] = 0u; return; }
}

// ---------------- xg GEMM: xg[slot*32+b][g] = sum_i x[t][b][i] * Wih[g][i] ----------------
// 128x128 tile, BK=32, 256 threads (4 waves, each 64x64 as 4x4 16x16 tiles)
__global__ __launch_bounds__(256) void gemm_xg(
    const ushort* __restrict__ xb,
    const ushort* __restrict__ wihf, const ushort* __restrict__ wihb,
    _Float16* __restrict__ xgf, _Float16* __restrict__ xgb,
    int s0)
{
    __shared__ ushort As[128 * 32];
    __shared__ ushort Bs[128 * 32];
    const int dir = blockIdx.z;
    const ushort* __restrict__ W = dir ? wihb : wihf;
    _Float16* __restrict__ xg = dir ? xgb : xgf;
    const int mBlk = blockIdx.x, nBlk = blockIdx.y;
    const int tid = threadIdx.x;
    const int w = tid >> 6, l = tid & 63;
    const int q = l >> 4, ml = l & 15;

    f32x4 acc[4][4];
    const f32x4 zero = {0.f, 0.f, 0.f, 0.f};
#pragma unroll
    for (int i = 0; i < 4; ++i)
#pragma unroll
        for (int j = 0; j < 4; ++j) acc[i][j] = zero;

    for (int kb = 0; kb < 32; ++kb) {
        // stage A and B tiles: 512 chunks of 16B each, 2 per thread
#pragma unroll
        for (int it = 0; it < 2; ++it) {
            int idx = tid + 256 * it;           // 0..511
            int rl = idx >> 2, kc = idx & 3;
            int gr = mBlk * 128 + rl;           // row in slot-space
            int slot = gr >> 5, bb = gr & 31;
            int t = dir ? (511 - s0 - slot) : (s0 + slot);
            const ushort* ga = xb + (size_t)(t * 32 + bb) * 1024 + kb * 32 + kc * 8;
            *(short8*)(As + idx * 8) = *(const short8*)ga;
            int colg = nBlk * 128 + rl;
            const ushort* gb = W + (size_t)colg * 1024 + kb * 32 + kc * 8;
            *(short8*)(Bs + idx * 8) = *(const short8*)gb;
        }
        __syncthreads();
        short8 af[4], bfr[4];
#pragma unroll
        for (int i = 0; i < 4; ++i)
            af[i] = *(const short8*)(As + ((w & 1) * 64 + i * 16 + ml) * 32 + q * 8);
#pragma unroll
        for (int j = 0; j < 4; ++j)
            bfr[j] = *(const short8*)(Bs + ((w >> 1) * 64 + j * 16 + ml) * 32 + q * 8);
#pragma unroll
        for (int i = 0; i < 4; ++i)
#pragma unroll
            for (int j = 0; j < 4; ++j)
                acc[i][j] = __builtin_amdgcn_mfma_f32_16x16x32_bf16(af[i], bfr[j], acc[i][j], 0, 0, 0);
        __syncthreads();
    }
    // epilogue: C/D layout col=lane&15, row=(lane>>4)*4+reg
#pragma unroll
    for (int i = 0; i < 4; ++i)
#pragma unroll
        for (int j = 0; j < 4; ++j)
#pragma unroll
            for (int rr = 0; rr < 4; ++rr) {
                int row = mBlk * 128 + (w & 1) * 64 + i * 16 + q * 4 + rr;
                int col = nBlk * 128 + (w >> 1) * 64 + j * 16 + ml;
                xg[(size_t)row * 4096 + col] = (_Float16)acc[i][j][rr];
            }
}

// ---------------- recurrence: cooperative, 256 blocks (128 per dir) ----------------
// block p of dir d owns h-cols [p*8, p*8+8) and gate cols {g*1024 + p*8 + r}
// B-frags (Whh slice, 32 cols x 1024 K) persist in VGPRs. Per step:
//   stage h (bf16) to LDS in 2 halves, 32 MFMA 16x16x32, gate exchange in LDS,
//   elementwise LSTM update, h write (double-buffered), per-dir device barrier.
__global__ __launch_bounds__(256) void rec_kernel(
    const ushort* __restrict__ whhf, const ushort* __restrict__ whhb,
    const _Float16* __restrict__ xgf, const _Float16* __restrict__ xgb,
    const float* __restrict__ bsumf, const float* __restrict__ bsumb,
    const float* __restrict__ c0f, const float* __restrict__ c0b,
    ushort* __restrict__ hbuf, float* __restrict__ cbuf,
    float* __restrict__ out, uint* __restrict__ flags,
    int s0, int csteps)
{
    __shared__ ushort Abuf[32 * 520];   // 32 rows x 512 k-half, stride 520 (pad vs bank aliasing)
    __shared__ float gbuf[32][33];

    const int bx = blockIdx.x;
    const int dir = bx >> 7;
    const int p = bx & 127;
    const int tid = threadIdx.x;
    const int w = tid >> 6, l = tid & 63;
    const int q = l >> 4, ml = l & 15;
    const int mt = w >> 1, nt = w & 1;

    const ushort* W = dir ? whhb : whhf;
    const _Float16* xg = dir ? xgb : xgf;
    const float* bsum = dir ? bsumb : bsumf;
    uint* ctr = flags + dir * 32;
    uint* gen = flags + dir * 32 + 16;

    // B-fragment preload: B[k=q*8+j][n=lane&15], n_local -> gate col
    const int n_local = nt * 16 + ml;
    const int gate_n = n_local >> 3, rn = n_local & 7;
    const size_t gcol = (size_t)(gate_n * 1024 + p * 8 + rn);
    const ushort* wrow = W + gcol * 1024;
    short8 bfrag[32];
#pragma unroll
    for (int kk = 0; kk < 32; ++kk)
        bfrag[kk] = *(const short8*)(wrow + kk * 32 + q * 8);

    // elementwise identity of this thread
    const int be = tid >> 3, re = tid & 7;
    const int hcol = p * 8 + re;
    const float bs0 = bsum[hcol], bs1 = bsum[1024 + hcol], bs2 = bsum[2048 + hcol], bs3 = bsum[3072 + hcol];
    float c = (s0 == 0) ? ((dir ? c0b : c0f)[be * 1024 + hcol])
                        : cbuf[dir * 32768 + be * 1024 + hcol];

    const f32x4 zero = {0.f, 0.f, 0.f, 0.f};

    for (int s = s0; s < s0 + csteps; ++s) {
        const int parity = s & 1;
        const ushort* hsrc = hbuf + (size_t)(dir * 2 + parity) * 32768;
        f32x4 acc0 = zero, acc1 = zero;
#pragma unroll
        for (int hf = 0; hf < 2; ++hf) {
            // stage 32 rows x 512 k (32KB): 2048 x 16B chunks, 8 per thread
#pragma unroll
            for (int it = 0; it < 8; ++it) {
                int idx = tid + 256 * it;
                int row = idx >> 6, kc = idx & 63;
                *(short8*)(Abuf + row * 520 + kc * 8) =
                    *(const short8*)(hsrc + row * 1024 + hf * 512 + kc * 8);
            }
            __syncthreads();
#pragma unroll
            for (int kk2 = 0; kk2 < 16; ++kk2) {
                short8 a = *(const short8*)(Abuf + (mt * 16 + ml) * 520 + kk2 * 32 + q * 8);
                int kk = hf * 16 + kk2;
                if (kk & 1) acc1 = __builtin_amdgcn_mfma_f32_16x16x32_bf16(a, bfrag[kk], acc1, 0, 0, 0);
                else        acc0 = __builtin_amdgcn_mfma_f32_16x16x32_bf16(a, bfrag[kk], acc0, 0, 0, 0);
            }
            __syncthreads();
        }
        // gates -> LDS (C/D layout: row = batch = mt*16 + q*4 + rr, col = n_local)
#pragma unroll
        for (int rr = 0; rr < 4; ++rr)
            gbuf[mt * 16 + q * 4 + rr][n_local] = acc0[rr] + acc1[rr];
        __syncthreads();

        const int t = dir ? (511 - s) : s;
        const int slot = s - s0;
        const _Float16* xrow = xg + ((size_t)slot * 32 + be) * 4096;
        float gi = gbuf[be][re]      + bs0 + (float)xrow[hcol];
        float gf = gbuf[be][8 + re]  + bs1 + (float)xrow[1024 + hcol];
        float gg = gbuf[be][16 + re] + bs2 + (float)xrow[2048 + hcol];
        float go = gbuf[be][24 + re] + bs3 + (float)xrow[3072 + hcol];
        float ii = sigmoidf_(gi), ff = sigmoidf_(gf), g2 = tanhf(gg), oo = sigmoidf_(go);
        c = ff * c + ii * g2;
        float h = oo * tanhf(c);
        out[(size_t)t * 65536 + be * 2048 + dir * 1024 + hcol] = h;
        hbuf[(size_t)(dir * 2 + (1 - parity)) * 32768 + be * 1024 + hcol] = f2bf(h);
        if (s == 511) {
            float* fin = out + 33554432 + dir * 65536;   // hf,cf then hb,cb
            fin[be * 1024 + hcol] = h;
            fin[32768 + be * 1024 + hcol] = c;
        }

        // per-dir device barrier (sense via monotonically increasing generation)
        __syncthreads();
        if (tid == 0) {
            __threadfence();  // make this block's h stores agent-visible
            uint expected = (uint)(s + 1);
            uint old = __hip_atomic_fetch_add(ctr, 1u, __ATOMIC_ACQ_REL, __HIP_MEMORY_SCOPE_AGENT);
            if (old == 127u) {
                __hip_atomic_store(ctr, 0u, __ATOMIC_RELAXED, __HIP_MEMORY_SCOPE_AGENT);
                __hip_atomic_store(gen, expected, __ATOMIC_RELEASE, __HIP_MEMORY_SCOPE_AGENT);
            }
            while (__hip_atomic_load(gen, __ATOMIC_ACQUIRE, __HIP_MEMORY_SCOPE_AGENT) < expected) {
                __builtin_amdgcn_s_sleep(2);
            }
        }
        __syncthreads();
    }
    cbuf[dir * 32768 + be * 1024 + hcol] = c;
}

// ---------------- host ----------------
extern "C" void kernel_launch(void* const* d_in, const int* in_sizes, int n_in,
                              void* d_out, int out_size, void* d_ws, size_t ws_size,
                              hipStream_t stream)
{
    const float* x     = (const float*)d_in[0];
    const float* h0f   = (const float*)d_in[1];
    const float* c0f   = (const float*)d_in[2];
    const float* h0b   = (const float*)d_in[3];
    const float* c0b   = (const float*)d_in[4];
    const float* wih_f = (const float*)d_in[5];
    const float* whh_f = (const float*)d_in[6];
    const float* bih_f = (const float*)d_in[7];
    const float* bhh_f = (const float*)d_in[8];
    const float* wih_b = (const float*)d_in[9];
    const float* whh_b = (const float*)d_in[10];
    const float* bih_b = (const float*)d_in[11];
    const float* bhh_b = (const float*)d_in[12];
    float* out = (float*)d_out;
    char* ws = (char*)d_ws;

    // choose chunking so fp16 xg fits in ws
    int csteps = 16;
    const int cands[6] = {512, 256, 128, 64, 32, 16};
    for (int i = 0; i < 6; ++i) {
        size_t need = OFF_XG + 2ull * (size_t)cands[i] * 262144ull;
        if (need <= ws_size) { csteps = cands[i]; break; }
    }

    prep_kernel<<<131361, 256, 0, stream>>>(x, wih_f, whh_f, bih_f, bhh_f,
                                            wih_b, whh_b, bih_b, bhh_b, h0f, h0b, ws);

    const ushort* xb    = (const ushort*)(ws + OFF_XB);
    const ushort* wihfb = (const ushort*)(ws + OFF_WIH_F);
    const ushort* wihbb = (const ushort*)(ws + OFF_WIH_B);
    const ushort* whhfb = (const ushort*)(ws + OFF_WHH_F);
    const ushort* whhbb = (const ushort*)(ws + OFF_WHH_B);
    const float*  bsf   = (const float*)(ws + OFF_BSUM_F);
    const float*  bsb   = (const float*)(ws + OFF_BSUM_B);
    ushort* hb          = (ushort*)(ws + OFF_HBUF);
    float*  cb          = (float*)(ws + OFF_CBUF);
    uint*   flagsp      = (uint*)(ws + OFF_FLAGS);
    _Float16* xgfp      = (_Float16*)(ws + OFF_XG);
    _Float16* xgbp      = (_Float16*)(ws + OFF_XG + (size_t)csteps * 262144ull);

    const int nchunks = 512 / csteps;
    for (int cidx = 0; cidx < nchunks; ++cidx) {
        int s0 = cidx * csteps;
        gemm_xg<<<dim3(csteps / 4, 32, 2), 256, 0, stream>>>(xb, wihfb, wihbb, xgfp, xgbp, s0);

        const ushort* a0 = whhfb; const ushort* a1 = whhbb;
        const _Float16* a2 = xgfp; const _Float16* a3 = xgbp;
        const float* a4 = bsf; const float* a5 = bsb;
        const float* a6 = c0f; const float* a7 = c0b;
        ushort* a8 = hb; float* a9 = cb; float* a10 = out; uint* a11 = flagsp;
        int a12 = s0, a13 = csteps;
        void* args[] = {&a0, &a1, &a2, &a3, &a4, &a5, &a6, &a7, &a8, &a9, &a10, &a11, &a12, &a13};
        hipLaunchCooperativeKernel((void*)rec_kernel, dim3(256), dim3(256), args, 0, stream);
    }
}